// Round 1
// baseline (489.944 us; speedup 1.0000x reference)
//
#include <hip/hip_runtime.h>
#include <hip/hip_bf16.h>
#include <stdint.h>

// EdgeConv: out[i] = max_k theta[src[i,k]] + feat @ (W_phi - W_theta)
// N=65536, F=512, K=16.
//
// Pipeline:
//  k_convert_feat : feat f32 -> bf16 (ws, 64MB), nt loads
//  k_prep_w       : Wcat^T (1024x512) bf16, LDS-transposed; cols 512.. hold
//                   (W_phi - W_theta)^T so GEMM directly produces delta
//  k_gemm         : 128x128 bf16 MFMA tile, XCD-swizzled blockIdx;
//                   2-phase double-buffered LDS (stage t+1 overlaps MFMA t,
//                   one barrier per K-step); OPERAND-SWAPPED MFMA
//                   (acc = mfma(B,A)) so each lane holds 4 consecutive
//                   COLUMNS per reg quad -> packed ushort4/f32x4 epilogue
//                   (16 stores/thread instead of 128).
//                   theta written in SLAB layout: 16 slabs of [N x 32] bf16
//                   (4 MB each == one XCD L2); delta f32 -> d_out
//  k_gather       : column-sliced + XCD-affine + PHASE-SPLIT: block b ->
//                   XCD b%8; processes its 256-row chunk for slice xcd
//                   first, then slice xcd+8, so each XCD's concurrent
//                   theta working set is ~one 4MB slab (L2-resident).
//                   delta-read / out-write are non-temporal.

typedef __bf16 bf16x8 __attribute__((ext_vector_type(8)));
typedef float f32x4 __attribute__((ext_vector_type(4)));

__device__ __forceinline__ unsigned short f2bf(float x) {
    unsigned u = __float_as_uint(x);
    unsigned r = u + 0x7fffu + ((u >> 16) & 1u);   // RNE
    return (unsigned short)(r >> 16);
}

__device__ __forceinline__ void async_ld16(const void* g, void* l) {
    __builtin_amdgcn_global_load_lds(
        (const __attribute__((address_space(1))) unsigned int*)g,
        (__attribute__((address_space(3))) unsigned int*)l,
        16, 0, 0);
}

// ---------------- feat f32 -> bf16 ----------------
__global__ void k_convert_feat(const float* __restrict__ feat,
                               unsigned short* __restrict__ featb) {
    int i = (blockIdx.x * 256 + threadIdx.x) * 4;
    f32x4 f = __builtin_nontemporal_load((const f32x4*)(feat + i));
    ushort4 o;
    o.x = f2bf(f.x); o.y = f2bf(f.y); o.z = f2bf(f.z); o.w = f2bf(f.w);
    *(ushort4*)(featb + i) = o;
}

// ---------------- Wcat^T via LDS transpose ----------------
// wtc[n][k]:  n<512 -> Wth[k][n] ;  n>=512 -> Wph[k][n-512] - Wth[k][n-512]
__global__ void k_prep_w(const float* __restrict__ Wth,
                         const float* __restrict__ Wph,
                         unsigned short* __restrict__ wtc) {
    __shared__ float tile[32][33];
    const int k0 = (blockIdx.x & 15) * 32;
    const int n0 = (blockIdx.x >> 4) * 32;
    const int t  = threadIdx.x;
    const int cc = t & 31;
    const int r0 = t >> 5;
#pragma unroll
    for (int it = 0; it < 4; ++it) {
        const int r  = it * 8 + r0;
        const int gn = n0 + cc;
        float v;
        if (gn < 512) v = Wth[(k0 + r) * 512 + gn];
        else          v = Wph[(k0 + r) * 512 + (gn - 512)] - Wth[(k0 + r) * 512 + (gn - 512)];
        tile[r][cc] = v;
    }
    __syncthreads();
#pragma unroll
    for (int it = 0; it < 4; ++it) {
        const int r2 = t & 31;
        const int c2 = it * 8 + (t >> 5);
        wtc[(size_t)(n0 + c2) * 512 + k0 + r2] = f2bf(tile[r2][c2]);
    }
}

// ---------------- bf16 MFMA GEMM: C (N x 1024) = featb @ Wcat ----------------
// 128x128 tile, BK=32, 256 thr = 4 waves (2x2 of 64x64), 16x16x32 MFMA.
// Double-buffered LDS, 2-phase pipeline (stage next tile before compute,
// single __syncthreads per step drains vmcnt for the in-flight loads).
// OPERAND-SWAPPED: acc[i][j] = mfma(bfr[j], af[i], acc) computes C^T tile:
//   D reg-dim (quad*4+r) = n, D lane-dim (lane&15) = m   [m89 layout, swapped]
// -> per (i,j): 4 consecutive n per lane -> ushort4 theta / f32x4 delta store.
__global__ __launch_bounds__(256, 3)
void k_gemm(const unsigned short* __restrict__ A,   // N x 512 bf16
            const unsigned short* __restrict__ Bt,  // 1024 x 512 bf16
            unsigned short* __restrict__ theta,     // 16 slabs of N x 32
            float* __restrict__ delta_f,            // N x 512 f32
            size_t slabStride)
{
    __shared__ __align__(16) unsigned short As[2][128 * 32];
    __shared__ __align__(16) unsigned short Bs[2][128 * 32];

    const int tid  = threadIdx.x;
    const int wave = tid >> 6;
    const int lane = tid & 63;
    const int quad = lane >> 4;
    const int l15  = lane & 15;

    const int b  = blockIdx.x;
    const int mt = (b >> 6) * 8 + (b & 7);
    const int nt = (b >> 3) & 7;
    const int m0 = mt * 128;
    const int n0 = nt * 128;

    const int wm = wave >> 1;
    const int wn = wave & 1;

    f32x4 acc[4][4];
#pragma unroll
    for (int i = 0; i < 4; i++)
#pragma unroll
        for (int j = 0; j < 4; j++) acc[i][j] = (f32x4){0.f, 0.f, 0.f, 0.f};

    const int r0   = (wave * 2 + 0) * 16 + (lane >> 2);
    const int r1   = (wave * 2 + 1) * 16 + (lane >> 2);
    const int koff = (lane & 3) * 8;

    const unsigned short* Ag0 = A  + (size_t)(m0 + r0) * 512 + koff;
    const unsigned short* Ag1 = A  + (size_t)(m0 + r1) * 512 + koff;
    const unsigned short* Bg0 = Bt + (size_t)(n0 + r0) * 512 + koff;
    const unsigned short* Bg1 = Bt + (size_t)(n0 + r1) * 512 + koff;

    unsigned short* const sA = &As[0][0];
    unsigned short* const sB = &Bs[0][0];
    const int oA0 = (wave * 2 + 0) * 512;   // lane*8 added by DMA
    const int oA1 = (wave * 2 + 1) * 512;

#define STAGE(buf, kg) do {                              \
        async_ld16(Ag0 + (kg), sA + (buf) * 4096 + oA0); \
        async_ld16(Ag1 + (kg), sA + (buf) * 4096 + oA1); \
        async_ld16(Bg0 + (kg), sB + (buf) * 4096 + oA0); \
        async_ld16(Bg1 + (kg), sB + (buf) * 4096 + oA1); \
    } while (0)

    STAGE(0, 0);
    __syncthreads();   // drain prologue loads

#pragma unroll
    for (int kt = 0; kt < 16; ++kt) {
        const int cur = kt & 1;
        if (kt < 15) STAGE(cur ^ 1, (kt + 1) * 32);   // overlaps MFMA below

        bf16x8 af[4], bfr[4];
#pragma unroll
        for (int t = 0; t < 4; ++t) {
            const int am = wm * 64 + t * 16 + l15;
            af[t]  = *(const bf16x8*)&sA[cur * 4096 + am * 32 + quad * 8];
            const int bn = wn * 64 + t * 16 + l15;
            bfr[t] = *(const bf16x8*)&sB[cur * 4096 + bn * 32 + quad * 8];
        }
#pragma unroll
        for (int i = 0; i < 4; i++)
#pragma unroll
            for (int j = 0; j < 4; j++)
                acc[i][j] = __builtin_amdgcn_mfma_f32_16x16x32_bf16(bfr[j], af[i], acc[i][j], 0, 0, 0);

        if (kt < 15) __syncthreads();   // drains vmcnt (next tile) + lgkm
    }
#undef STAGE

    // Swapped D layout: m = lane&15 dim, n = quad*4 + reg dim
    const bool is_theta = (n0 < 512);
#pragma unroll
    for (int i = 0; i < 4; i++) {
        const int m = m0 + wm * 64 + i * 16 + l15;
#pragma unroll
        for (int j = 0; j < 4; j++) {
            const int nb = n0 + wn * 64 + j * 16 + quad * 4;
            const f32x4 v = acc[i][j];
            if (is_theta) {
                ushort4 o;
                o.x = f2bf(v[0]); o.y = f2bf(v[1]);
                o.z = f2bf(v[2]); o.w = f2bf(v[3]);
                *(ushort4*)&theta[(size_t)(nb >> 5) * slabStride
                                  + (size_t)m * 32 + (nb & 31)] = o;
            } else {
                *(f32x4*)&delta_f[(size_t)m * 512 + (nb - 512)] = v;
            }
        }
    }
}

// ---------------- column-sliced gather + max + combine ----------------
// grid = 8 xcd-lanes x (N/256) chunks. Block b: xcd = b&7, chunk = b>>3.
// Phase-split: process chunk rows for slice xcd (passes 0..3), then slice
// xcd+8 -> concurrent theta working set per XCD ~= one 4MB slab (fits L2).
// Each pass: 64 rows x 32 cols; 256 thr = 4 thr/row; 8 cols (16B) per gather.
__global__ void k_gather(const unsigned short* __restrict__ theta,
                         float* out,                      // holds delta f32 on entry
                         const int* __restrict__ src,
                         const int* __restrict__ kptr,
                         size_t slabStride)
{
    const int b     = blockIdx.x;
    const int xcd   = b & 7;
    const int chunk = b >> 3;                    // 0 .. N/256-1
    const int kk    = *kptr;

    const int tid = threadIdx.x;
    const int c8  = (tid & 3) * 8;               // col within 32-wide slice
    const int rly = tid >> 2;                    // 0..63

    for (int half = 0; half < 2; ++half) {
        const int slice = half * 8 + xcd;
        const unsigned short* slab = theta + (size_t)slice * slabStride;

#pragma unroll 2
        for (int pass = 0; pass < 4; ++pass) {
            const int row = chunk * 256 + pass * 64 + rly;

            float m0 = -INFINITY, m1 = -INFINITY, m2 = -INFINITY, m3 = -INFINITY;
            float m4 = -INFINITY, m5 = -INFINITY, m6 = -INFINITY, m7 = -INFINITY;

            if (kk == 16) {
                const int4* sp = (const int4*)(src + (size_t)row * 16);
                int4 sv[4];
                sv[0] = sp[0]; sv[1] = sp[1]; sv[2] = sp[2]; sv[3] = sp[3];
#pragma unroll
                for (int q = 0; q < 4; ++q) {
                    const int ss[4] = {sv[q].x, sv[q].y, sv[q].z, sv[q].w};
#pragma unroll
                    for (int j = 0; j < 4; ++j) {
                        const uint4 v = *(const uint4*)(slab + (size_t)ss[j] * 32 + c8);
                        m0 = fmaxf(m0, __uint_as_float(v.x << 16));
                        m1 = fmaxf(m1, __uint_as_float(v.x & 0xffff0000u));
                        m2 = fmaxf(m2, __uint_as_float(v.y << 16));
                        m3 = fmaxf(m3, __uint_as_float(v.y & 0xffff0000u));
                        m4 = fmaxf(m4, __uint_as_float(v.z << 16));
                        m5 = fmaxf(m5, __uint_as_float(v.z & 0xffff0000u));
                        m6 = fmaxf(m6, __uint_as_float(v.w << 16));
                        m7 = fmaxf(m7, __uint_as_float(v.w & 0xffff0000u));
                    }
                }
            } else {
                for (int k = 0; k < kk; ++k) {
                    const int s = src[(size_t)row * 16 + k];
                    const uint4 v = *(const uint4*)(slab + (size_t)s * 32 + c8);
                    m0 = fmaxf(m0, __uint_as_float(v.x << 16));
                    m1 = fmaxf(m1, __uint_as_float(v.x & 0xffff0000u));
                    m2 = fmaxf(m2, __uint_as_float(v.y << 16));
                    m3 = fmaxf(m3, __uint_as_float(v.y & 0xffff0000u));
                    m4 = fmaxf(m4, __uint_as_float(v.z << 16));
                    m5 = fmaxf(m5, __uint_as_float(v.z & 0xffff0000u));
                    m6 = fmaxf(m6, __uint_as_float(v.w << 16));
                    m7 = fmaxf(m7, __uint_as_float(v.w & 0xffff0000u));
                }
            }

            float* op = out + (size_t)row * 512 + slice * 32 + c8;
            const f32x4 d0 = __builtin_nontemporal_load((const f32x4*)op);
            const f32x4 d1 = __builtin_nontemporal_load((const f32x4*)op + 1);
            f32x4 o0, o1;
            o0[0] = m0 + d0[0]; o0[1] = m1 + d0[1]; o0[2] = m2 + d0[2]; o0[3] = m3 + d0[3];
            o1[0] = m4 + d1[0]; o1[1] = m5 + d1[1]; o1[2] = m6 + d1[2]; o1[3] = m7 + d1[3];
            __builtin_nontemporal_store(o0, (f32x4*)op);
            __builtin_nontemporal_store(o1, (f32x4*)op + 1);
        }
    }
}

extern "C" void kernel_launch(void* const* d_in, const int* in_sizes, int n_in,
                              void* d_out, int out_size, void* d_ws, size_t ws_size,
                              hipStream_t stream) {
    const int*   kptr = (const int*)d_in[0];
    const int*   src  = (const int*)d_in[1];
    const float* feat = (const float*)d_in[2];
    const float* Wth  = (const float*)d_in[3];
    const float* Wph  = (const float*)d_in[4];
    float* out = (float*)d_out;

    const int N = in_sizes[2] / 512;            // 65536
    const size_t slabStride = (size_t)N * 32;   // elems per 32-col slab

    // ws layout: featb 64MB | wtc 1MB | theta slabs 64MB  (129 MB total)
    unsigned short* featb = (unsigned short*)d_ws;
    unsigned short* wtc   = (unsigned short*)((char*)d_ws + (size_t)64 * 1024 * 1024);
    unsigned short* table = (unsigned short*)((char*)d_ws + (size_t)65 * 1024 * 1024);

    k_convert_feat<<<(N * 512) / 1024, 256, 0, stream>>>(feat, featb);
    k_prep_w<<<512, 256, 0, stream>>>(Wth, Wph, wtc);
    k_gemm<<<(N / 128) * 8, 256, 0, stream>>>(featb, wtc, table, out, slabStride);
    k_gather<<<8 * (N / 256), 256, 0, stream>>>(table, out, src, kptr, slabStride);
}

// Round 2
// 458.757 us; speedup vs baseline: 1.0680x; 1.0680x over previous
//
#include <hip/hip_runtime.h>
#include <hip/hip_bf16.h>
#include <stdint.h>

// EdgeConv: out[i] = max_k theta[src[i,k]] + feat @ (W_phi - W_theta)
// N=65536, F=512, K=16.
//
// Pipeline:
//  k_convert_feat : feat f32 -> bf16 (ws, 64MB), nt loads
//  k_prep_w       : Wcat^T (1024x512) bf16, LDS-transposed; cols 512.. hold
//                   (W_phi - W_theta)^T so GEMM directly produces delta
//  k_gemm         : 128x128 bf16 MFMA tile, XCD-swizzled blockIdx.
//                   3-buffer LDS pipeline, COUNTED vmcnt (never vmcnt(0)
//                   in the loop), ONE raw s_barrier per K-step:
//                     iter kt: STAGE(kt+2) | ds_read(kt) | MFMA |
//                              sched_barrier | vmcnt(4) | s_barrier
//                   Operand-swapped MFMA (acc = mfma(B,A)) -> lane holds 4
//                   consecutive COLUMNS -> packed ushort4/f32x4 epilogue.
//                   theta written in SLAB layout: 16 slabs of [N x 32] bf16
//                   (4 MB each == one XCD L2); delta f32 -> d_out
//  k_gather       : column-sliced + XCD-affine (round-0 proven version):
//                   block b -> XCD b%8 handles slice (phase*8 + b%8);
//                   512 rows x 32 cols per block; nt delta-read/out-write.

typedef __bf16 bf16x8 __attribute__((ext_vector_type(8)));
typedef float f32x4 __attribute__((ext_vector_type(4)));

__device__ __forceinline__ unsigned short f2bf(float x) {
    unsigned u = __float_as_uint(x);
    unsigned r = u + 0x7fffu + ((u >> 16) & 1u);   // RNE
    return (unsigned short)(r >> 16);
}

__device__ __forceinline__ void async_ld16(const void* g, void* l) {
    __builtin_amdgcn_global_load_lds(
        (const __attribute__((address_space(1))) unsigned int*)g,
        (__attribute__((address_space(3))) unsigned int*)l,
        16, 0, 0);
}

// ---------------- feat f32 -> bf16 ----------------
__global__ void k_convert_feat(const float* __restrict__ feat,
                               unsigned short* __restrict__ featb) {
    int i = (blockIdx.x * 256 + threadIdx.x) * 4;
    f32x4 f = __builtin_nontemporal_load((const f32x4*)(feat + i));
    ushort4 o;
    o.x = f2bf(f.x); o.y = f2bf(f.y); o.z = f2bf(f.z); o.w = f2bf(f.w);
    *(ushort4*)(featb + i) = o;
}

// ---------------- Wcat^T via LDS transpose ----------------
// wtc[n][k]:  n<512 -> Wth[k][n] ;  n>=512 -> Wph[k][n-512] - Wth[k][n-512]
__global__ void k_prep_w(const float* __restrict__ Wth,
                         const float* __restrict__ Wph,
                         unsigned short* __restrict__ wtc) {
    __shared__ float tile[32][33];
    const int k0 = (blockIdx.x & 15) * 32;
    const int n0 = (blockIdx.x >> 4) * 32;
    const int t  = threadIdx.x;
    const int cc = t & 31;
    const int r0 = t >> 5;
#pragma unroll
    for (int it = 0; it < 4; ++it) {
        const int r  = it * 8 + r0;
        const int gn = n0 + cc;
        float v;
        if (gn < 512) v = Wth[(k0 + r) * 512 + gn];
        else          v = Wph[(k0 + r) * 512 + (gn - 512)] - Wth[(k0 + r) * 512 + (gn - 512)];
        tile[r][cc] = v;
    }
    __syncthreads();
#pragma unroll
    for (int it = 0; it < 4; ++it) {
        const int r2 = t & 31;
        const int c2 = it * 8 + (t >> 5);
        wtc[(size_t)(n0 + c2) * 512 + k0 + r2] = f2bf(tile[r2][c2]);
    }
}

// ---------------- bf16 MFMA GEMM: C (N x 1024) = featb @ Wcat ----------------
// 128x128 tile, BK=32, 256 thr = 4 waves (2x2 of 64x64), 16x16x32 MFMA.
// 3-buffer pipeline, counted vmcnt(4): stage(kt+2) in flight across the
// barrier while computing kt; buffer (kt+2)%3 == (kt-1)%3 was consumed
// before the end-of-(kt-1) barrier (sched_barrier pins MFMA+lgkm there).
__global__ __launch_bounds__(256, 3)
void k_gemm(const unsigned short* __restrict__ A,   // N x 512 bf16
            const unsigned short* __restrict__ Bt,  // 1024 x 512 bf16
            unsigned short* __restrict__ theta,     // 16 slabs of N x 32
            float* __restrict__ delta_f,            // N x 512 f32
            size_t slabStride)
{
    __shared__ __align__(16) unsigned short As[3][128 * 32];
    __shared__ __align__(16) unsigned short Bs[3][128 * 32];

    const int tid  = threadIdx.x;
    const int wave = tid >> 6;
    const int lane = tid & 63;
    const int quad = lane >> 4;
    const int l15  = lane & 15;

    const int b  = blockIdx.x;
    const int mt = (b >> 6) * 8 + (b & 7);
    const int nt = (b >> 3) & 7;
    const int m0 = mt * 128;
    const int n0 = nt * 128;

    const int wm = wave >> 1;
    const int wn = wave & 1;

    f32x4 acc[4][4];
#pragma unroll
    for (int i = 0; i < 4; i++)
#pragma unroll
        for (int j = 0; j < 4; j++) acc[i][j] = (f32x4){0.f, 0.f, 0.f, 0.f};

    const int r0   = (wave * 2 + 0) * 16 + (lane >> 2);
    const int r1   = (wave * 2 + 1) * 16 + (lane >> 2);
    const int koff = (lane & 3) * 8;

    const unsigned short* Ag0 = A  + (size_t)(m0 + r0) * 512 + koff;
    const unsigned short* Ag1 = A  + (size_t)(m0 + r1) * 512 + koff;
    const unsigned short* Bg0 = Bt + (size_t)(n0 + r0) * 512 + koff;
    const unsigned short* Bg1 = Bt + (size_t)(n0 + r1) * 512 + koff;

    const int oA0 = (wave * 2 + 0) * 512;   // lane*8 elems added by DMA
    const int oA1 = (wave * 2 + 1) * 512;

#define STAGE(buf, kg) do {                            \
        async_ld16(Ag0 + (kg), &As[(buf)][oA0]);       \
        async_ld16(Ag1 + (kg), &As[(buf)][oA1]);       \
        async_ld16(Bg0 + (kg), &Bs[(buf)][oA0]);       \
        async_ld16(Bg1 + (kg), &Bs[(buf)][oA1]);       \
    } while (0)

    // prologue: 2 tiles in flight, wait only the first (vmcnt(4))
    STAGE(0, 0);
    STAGE(1, 32);
    asm volatile("s_waitcnt vmcnt(4)" ::: "memory");
    __builtin_amdgcn_s_barrier();

#pragma unroll
    for (int kt = 0; kt < 16; ++kt) {
        const int cur = kt % 3;
        if (kt < 14) STAGE((kt + 2) % 3, (kt + 2) * 32);

        bf16x8 af[4], bfr[4];
#pragma unroll
        for (int t = 0; t < 4; ++t) {
            const int am = wm * 64 + t * 16 + l15;
            af[t]  = *(const bf16x8*)&As[cur][am * 32 + quad * 8];
            const int bn = wn * 64 + t * 16 + l15;
            bfr[t] = *(const bf16x8*)&Bs[cur][bn * 32 + quad * 8];
        }
#pragma unroll
        for (int i = 0; i < 4; i++)
#pragma unroll
            for (int j = 0; j < 4; j++)
                acc[i][j] = __builtin_amdgcn_mfma_f32_16x16x32_bf16(bfr[j], af[i], acc[i][j], 0, 0, 0);

        if (kt < 15) {
            // pin MFMAs (and their lgkm waits) above the barrier so no wave
            // crosses it with pending reads of buffer `cur` (overwritten at kt+1)
            __builtin_amdgcn_sched_barrier(0);
            if (kt < 14) asm volatile("s_waitcnt vmcnt(4)" ::: "memory");
            else         asm volatile("s_waitcnt vmcnt(0)" ::: "memory");
            __builtin_amdgcn_s_barrier();
        }
    }
#undef STAGE

    // Swapped D layout: m = lane&15 dim, n = quad*4 + reg dim
    const bool is_theta = (n0 < 512);
#pragma unroll
    for (int i = 0; i < 4; i++) {
        const int m = m0 + wm * 64 + i * 16 + l15;
#pragma unroll
        for (int j = 0; j < 4; j++) {
            const int nb = n0 + wn * 64 + j * 16 + quad * 4;
            const f32x4 v = acc[i][j];
            if (is_theta) {
                ushort4 o;
                o.x = f2bf(v[0]); o.y = f2bf(v[1]);
                o.z = f2bf(v[2]); o.w = f2bf(v[3]);
                *(ushort4*)&theta[(size_t)(nb >> 5) * slabStride
                                  + (size_t)m * 32 + (nb & 31)] = o;
            } else {
                *(f32x4*)&delta_f[(size_t)m * 512 + (nb - 512)] = v;
            }
        }
    }
}

// ---------------- column-sliced gather + max + combine (round-0 version) ----
// grid = 16 slices x (N/512) chunks. Block b: xcd = b&7; the first
// 8*chunksPerSlice blocks are phase 0 (slices 0..7), rest slices 8..15.
// Each block: 512 rows x 32 cols; 256 thr = 4 thr/row x 64 rows/pass, 8 passes.
// Per thread: 8 cols (16 B uint4 per gather).
__global__ void k_gather(const unsigned short* __restrict__ theta,
                         float* out,                      // holds delta f32 on entry
                         const int* __restrict__ src,
                         const int* __restrict__ kptr,
                         int chunksPerSlice, size_t slabStride)
{
    const int b     = blockIdx.x;
    const int xcd   = b & 7;
    const int t2    = b >> 3;
    const int chunk = t2 % chunksPerSlice;
    const int phase = t2 / chunksPerSlice;       // 0 or 1
    const int slice = phase * 8 + xcd;
    const int kk    = *kptr;

    const unsigned short* slab = theta + (size_t)slice * slabStride;
    const int tid = threadIdx.x;
    const int c8  = (tid & 3) * 8;               // col within 32-wide slice
    const int rly = tid >> 2;                    // 0..63

#pragma unroll 2
    for (int pass = 0; pass < 8; ++pass) {
        const int row = chunk * 512 + pass * 64 + rly;

        float m0 = -INFINITY, m1 = -INFINITY, m2 = -INFINITY, m3 = -INFINITY;
        float m4 = -INFINITY, m5 = -INFINITY, m6 = -INFINITY, m7 = -INFINITY;

        if (kk == 16) {
            const int4* sp = (const int4*)(src + (size_t)row * 16);
            int4 sv[4];
            sv[0] = sp[0]; sv[1] = sp[1]; sv[2] = sp[2]; sv[3] = sp[3];
#pragma unroll
            for (int q = 0; q < 4; ++q) {
                const int ss[4] = {sv[q].x, sv[q].y, sv[q].z, sv[q].w};
#pragma unroll
                for (int j = 0; j < 4; ++j) {
                    const uint4 v = *(const uint4*)(slab + (size_t)ss[j] * 32 + c8);
                    m0 = fmaxf(m0, __uint_as_float(v.x << 16));
                    m1 = fmaxf(m1, __uint_as_float(v.x & 0xffff0000u));
                    m2 = fmaxf(m2, __uint_as_float(v.y << 16));
                    m3 = fmaxf(m3, __uint_as_float(v.y & 0xffff0000u));
                    m4 = fmaxf(m4, __uint_as_float(v.z << 16));
                    m5 = fmaxf(m5, __uint_as_float(v.z & 0xffff0000u));
                    m6 = fmaxf(m6, __uint_as_float(v.w << 16));
                    m7 = fmaxf(m7, __uint_as_float(v.w & 0xffff0000u));
                }
            }
        } else {
            for (int k = 0; k < kk; ++k) {
                const int s = src[(size_t)row * 16 + k];
                const uint4 v = *(const uint4*)(slab + (size_t)s * 32 + c8);
                m0 = fmaxf(m0, __uint_as_float(v.x << 16));
                m1 = fmaxf(m1, __uint_as_float(v.x & 0xffff0000u));
                m2 = fmaxf(m2, __uint_as_float(v.y << 16));
                m3 = fmaxf(m3, __uint_as_float(v.y & 0xffff0000u));
                m4 = fmaxf(m4, __uint_as_float(v.z << 16));
                m5 = fmaxf(m5, __uint_as_float(v.z & 0xffff0000u));
                m6 = fmaxf(m6, __uint_as_float(v.w << 16));
                m7 = fmaxf(m7, __uint_as_float(v.w & 0xffff0000u));
            }
        }

        float* op = out + (size_t)row * 512 + slice * 32 + c8;
        const f32x4 d0 = __builtin_nontemporal_load((const f32x4*)op);
        const f32x4 d1 = __builtin_nontemporal_load((const f32x4*)op + 1);
        f32x4 o0, o1;
        o0[0] = m0 + d0[0]; o0[1] = m1 + d0[1]; o0[2] = m2 + d0[2]; o0[3] = m3 + d0[3];
        o1[0] = m4 + d1[0]; o1[1] = m5 + d1[1]; o1[2] = m6 + d1[2]; o1[3] = m7 + d1[3];
        __builtin_nontemporal_store(o0, (f32x4*)op);
        __builtin_nontemporal_store(o1, (f32x4*)op + 1);
    }
}

extern "C" void kernel_launch(void* const* d_in, const int* in_sizes, int n_in,
                              void* d_out, int out_size, void* d_ws, size_t ws_size,
                              hipStream_t stream) {
    const int*   kptr = (const int*)d_in[0];
    const int*   src  = (const int*)d_in[1];
    const float* feat = (const float*)d_in[2];
    const float* Wth  = (const float*)d_in[3];
    const float* Wph  = (const float*)d_in[4];
    float* out = (float*)d_out;

    const int N = in_sizes[2] / 512;            // 65536
    const size_t slabStride = (size_t)N * 32;   // elems per 32-col slab

    // ws layout: featb 64MB | wtc 1MB | theta slabs 64MB  (129 MB total)
    unsigned short* featb = (unsigned short*)d_ws;
    unsigned short* wtc   = (unsigned short*)((char*)d_ws + (size_t)64 * 1024 * 1024);
    unsigned short* table = (unsigned short*)((char*)d_ws + (size_t)65 * 1024 * 1024);

    const int chunksPerSlice = N / 512;

    k_convert_feat<<<(N * 512) / 1024, 256, 0, stream>>>(feat, featb);
    k_prep_w<<<512, 256, 0, stream>>>(Wth, Wph, wtc);
    k_gemm<<<(N / 128) * 8, 256, 0, stream>>>(featb, wtc, table, out, slabStride);
    k_gather<<<16 * chunksPerSlice, 256, 0, stream>>>(table, out, src, kptr,
                                                      chunksPerSlice, slabStride);
}

// Round 3
// 457.817 us; speedup vs baseline: 1.0702x; 1.0021x over previous
//
#include <hip/hip_runtime.h>
#include <hip/hip_bf16.h>
#include <stdint.h>

// EdgeConv: out[i] = max_k theta[src[i,k]] + feat @ (W_phi - W_theta)
// N=65536, F=512, K=16.
//
// Pipeline:
//  k_convert_feat : feat f32 -> bf16 (ws, 64MB), nt loads
//  k_prep_w       : Wcat^T (1024x512) bf16, LDS-transposed; cols 512.. hold
//                   (W_phi - W_theta)^T so GEMM directly produces delta
//  k_gemm         : 128x128 bf16 MFMA tile, XCD-swizzled blockIdx.
//                   3-buffer LDS pipeline, counted vmcnt, one s_barrier/step.
//                   T2 LDS XOR-SWIZZLE (this round): fragment reads were an
//                   8-way bank conflict (row stride 64B; 16 lanes/quad at the
//                   same 16B col -> 2 bank-quads). Fix per rule #21: linear
//                   LDS dest + pre-swizzled GLOBAL source col
//                   (ksw = col16 ^ ((row>>1)&3)) + same XOR on ds_read addr.
//                   Now each quad-group covers all 32 banks exactly 2x (floor).
//                   Operand-swapped MFMA -> packed ushort4/f32x4 epilogue.
//                   theta written in SLAB layout: 16 slabs of [N x 32] bf16
//                   (4 MB each == one XCD L2); delta f32 -> d_out
//  k_gather       : column-sliced + XCD-affine (round-0 proven version):
//                   block b -> XCD b%8 handles slice (phase*8 + b%8);
//                   512 rows x 32 cols per block; nt delta-read/out-write.

typedef __bf16 bf16x8 __attribute__((ext_vector_type(8)));
typedef float f32x4 __attribute__((ext_vector_type(4)));

__device__ __forceinline__ unsigned short f2bf(float x) {
    unsigned u = __float_as_uint(x);
    unsigned r = u + 0x7fffu + ((u >> 16) & 1u);   // RNE
    return (unsigned short)(r >> 16);
}

__device__ __forceinline__ void async_ld16(const void* g, void* l) {
    __builtin_amdgcn_global_load_lds(
        (const __attribute__((address_space(1))) unsigned int*)g,
        (__attribute__((address_space(3))) unsigned int*)l,
        16, 0, 0);
}

// ---------------- feat f32 -> bf16 ----------------
__global__ void k_convert_feat(const float* __restrict__ feat,
                               unsigned short* __restrict__ featb) {
    int i = (blockIdx.x * 256 + threadIdx.x) * 4;
    f32x4 f = __builtin_nontemporal_load((const f32x4*)(feat + i));
    ushort4 o;
    o.x = f2bf(f.x); o.y = f2bf(f.y); o.z = f2bf(f.z); o.w = f2bf(f.w);
    *(ushort4*)(featb + i) = o;
}

// ---------------- Wcat^T via LDS transpose ----------------
// wtc[n][k]:  n<512 -> Wth[k][n] ;  n>=512 -> Wph[k][n-512] - Wth[k][n-512]
__global__ void k_prep_w(const float* __restrict__ Wth,
                         const float* __restrict__ Wph,
                         unsigned short* __restrict__ wtc) {
    __shared__ float tile[32][33];
    const int k0 = (blockIdx.x & 15) * 32;
    const int n0 = (blockIdx.x >> 4) * 32;
    const int t  = threadIdx.x;
    const int cc = t & 31;
    const int r0 = t >> 5;
#pragma unroll
    for (int it = 0; it < 4; ++it) {
        const int r  = it * 8 + r0;
        const int gn = n0 + cc;
        float v;
        if (gn < 512) v = Wth[(k0 + r) * 512 + gn];
        else          v = Wph[(k0 + r) * 512 + (gn - 512)] - Wth[(k0 + r) * 512 + (gn - 512)];
        tile[r][cc] = v;
    }
    __syncthreads();
#pragma unroll
    for (int it = 0; it < 4; ++it) {
        const int r2 = t & 31;
        const int c2 = it * 8 + (t >> 5);
        wtc[(size_t)(n0 + c2) * 512 + k0 + r2] = f2bf(tile[r2][c2]);
    }
}

// ---------------- bf16 MFMA GEMM: C (N x 1024) = featb @ Wcat ----------------
// 128x128 tile, BK=32, 256 thr = 4 waves (2x2 of 64x64), 16x16x32 MFMA.
// 3-buffer pipeline, counted vmcnt(4); T2 swizzle on LDS cols (see header).
__global__ __launch_bounds__(256, 3)
void k_gemm(const unsigned short* __restrict__ A,   // N x 512 bf16
            const unsigned short* __restrict__ Bt,  // 1024 x 512 bf16
            unsigned short* __restrict__ theta,     // 16 slabs of N x 32
            float* __restrict__ delta_f,            // N x 512 f32
            size_t slabStride)
{
    __shared__ __align__(16) unsigned short As[3][128 * 32];
    __shared__ __align__(16) unsigned short Bs[3][128 * 32];

    const int tid  = threadIdx.x;
    const int wave = tid >> 6;
    const int lane = tid & 63;
    const int quad = lane >> 4;
    const int l15  = lane & 15;

    const int b  = blockIdx.x;
    const int mt = (b >> 6) * 8 + (b & 7);
    const int nt = (b >> 3) & 7;
    const int m0 = mt * 128;
    const int n0 = nt * 128;

    const int wm = wave >> 1;
    const int wn = wave & 1;

    f32x4 acc[4][4];
#pragma unroll
    for (int i = 0; i < 4; i++)
#pragma unroll
        for (int j = 0; j < 4; j++) acc[i][j] = (f32x4){0.f, 0.f, 0.f, 0.f};

    const int r0 = (wave * 2 + 0) * 16 + (lane >> 2);
    const int r1 = (wave * 2 + 1) * 16 + (lane >> 2);
    // Source col pre-swizzle (elems): 16B slot (lane&3) XOR'd with
    // ((row>>1)&3) = ((lane>>3)&3); rows +16 preserve the mask.
    const int ksw = ((lane & 3) << 3) ^ (((lane >> 3) & 3) << 3);

    const unsigned short* Ag0 = A  + (size_t)(m0 + r0) * 512 + ksw;
    const unsigned short* Ag1 = A  + (size_t)(m0 + r1) * 512 + ksw;
    const unsigned short* Bg0 = Bt + (size_t)(n0 + r0) * 512 + ksw;
    const unsigned short* Bg1 = Bt + (size_t)(n0 + r1) * 512 + ksw;

    const int oA0 = (wave * 2 + 0) * 512;   // lane*8 elems added by DMA
    const int oA1 = (wave * 2 + 1) * 512;

#define STAGE(buf, kg) do {                            \
        async_ld16(Ag0 + (kg), &As[(buf)][oA0]);       \
        async_ld16(Ag1 + (kg), &As[(buf)][oA1]);       \
        async_ld16(Bg0 + (kg), &Bs[(buf)][oA0]);       \
        async_ld16(Bg1 + (kg), &Bs[(buf)][oA1]);       \
    } while (0)

    // prologue: 2 tiles in flight, wait only the first (vmcnt(4))
    STAGE(0, 0);
    STAGE(1, 32);
    asm volatile("s_waitcnt vmcnt(4)" ::: "memory");
    __builtin_amdgcn_s_barrier();

    // Read-side swizzle: logical 16B slot `quad` at row am -> physical
    // slot quad ^ ((am>>1)&3); (am>>1)&3 == (l15>>1)&3 (W multiple of 16).
    const int rdoff = (quad << 3) ^ (((l15 >> 1) & 3) << 3);

#pragma unroll
    for (int kt = 0; kt < 16; ++kt) {
        const int cur = kt % 3;
        if (kt < 14) STAGE((kt + 2) % 3, (kt + 2) * 32);

        bf16x8 af[4], bfr[4];
#pragma unroll
        for (int t = 0; t < 4; ++t) {
            const int am = wm * 64 + t * 16 + l15;
            af[t]  = *(const bf16x8*)&As[cur][am * 32 + rdoff];
            const int bn = wn * 64 + t * 16 + l15;
            bfr[t] = *(const bf16x8*)&Bs[cur][bn * 32 + rdoff];
        }
#pragma unroll
        for (int i = 0; i < 4; i++)
#pragma unroll
            for (int j = 0; j < 4; j++)
                acc[i][j] = __builtin_amdgcn_mfma_f32_16x16x32_bf16(bfr[j], af[i], acc[i][j], 0, 0, 0);

        if (kt < 15) {
            // pin MFMAs (and their lgkm waits) above the barrier so no wave
            // crosses it with pending reads of buffer `cur` (overwritten at kt+1)
            __builtin_amdgcn_sched_barrier(0);
            if (kt < 14) asm volatile("s_waitcnt vmcnt(4)" ::: "memory");
            else         asm volatile("s_waitcnt vmcnt(0)" ::: "memory");
            __builtin_amdgcn_s_barrier();
        }
    }
#undef STAGE

    // Swapped D layout: m = lane&15 dim, n = quad*4 + reg dim
    const bool is_theta = (n0 < 512);
#pragma unroll
    for (int i = 0; i < 4; i++) {
        const int m = m0 + wm * 64 + i * 16 + l15;
#pragma unroll
        for (int j = 0; j < 4; j++) {
            const int nb = n0 + wn * 64 + j * 16 + quad * 4;
            const f32x4 v = acc[i][j];
            if (is_theta) {
                ushort4 o;
                o.x = f2bf(v[0]); o.y = f2bf(v[1]);
                o.z = f2bf(v[2]); o.w = f2bf(v[3]);
                *(ushort4*)&theta[(size_t)(nb >> 5) * slabStride
                                  + (size_t)m * 32 + (nb & 31)] = o;
            } else {
                *(f32x4*)&delta_f[(size_t)m * 512 + (nb - 512)] = v;
            }
        }
    }
}

// ---------------- column-sliced gather + max + combine (round-0 version) ----
// grid = 16 slices x (N/512) chunks. Block b: xcd = b&7; the first
// 8*chunksPerSlice blocks are phase 0 (slices 0..7), rest slices 8..15.
// Each block: 512 rows x 32 cols; 256 thr = 4 thr/row x 64 rows/pass, 8 passes.
// Per thread: 8 cols (16 B uint4 per gather).
__global__ void k_gather(const unsigned short* __restrict__ theta,
                         float* out,                      // holds delta f32 on entry
                         const int* __restrict__ src,
                         const int* __restrict__ kptr,
                         int chunksPerSlice, size_t slabStride)
{
    const int b     = blockIdx.x;
    const int xcd   = b & 7;
    const int t2    = b >> 3;
    const int chunk = t2 % chunksPerSlice;
    const int phase = t2 / chunksPerSlice;       // 0 or 1
    const int slice = phase * 8 + xcd;
    const int kk    = *kptr;

    const unsigned short* slab = theta + (size_t)slice * slabStride;
    const int tid = threadIdx.x;
    const int c8  = (tid & 3) * 8;               // col within 32-wide slice
    const int rly = tid >> 2;                    // 0..63

#pragma unroll 2
    for (int pass = 0; pass < 8; ++pass) {
        const int row = chunk * 512 + pass * 64 + rly;

        float m0 = -INFINITY, m1 = -INFINITY, m2 = -INFINITY, m3 = -INFINITY;
        float m4 = -INFINITY, m5 = -INFINITY, m6 = -INFINITY, m7 = -INFINITY;

        if (kk == 16) {
            const int4* sp = (const int4*)(src + (size_t)row * 16);
            int4 sv[4];
            sv[0] = sp[0]; sv[1] = sp[1]; sv[2] = sp[2]; sv[3] = sp[3];
#pragma unroll
            for (int q = 0; q < 4; ++q) {
                const int ss[4] = {sv[q].x, sv[q].y, sv[q].z, sv[q].w};
#pragma unroll
                for (int j = 0; j < 4; ++j) {
                    const uint4 v = *(const uint4*)(slab + (size_t)ss[j] * 32 + c8);
                    m0 = fmaxf(m0, __uint_as_float(v.x << 16));
                    m1 = fmaxf(m1, __uint_as_float(v.x & 0xffff0000u));
                    m2 = fmaxf(m2, __uint_as_float(v.y << 16));
                    m3 = fmaxf(m3, __uint_as_float(v.y & 0xffff0000u));
                    m4 = fmaxf(m4, __uint_as_float(v.z << 16));
                    m5 = fmaxf(m5, __uint_as_float(v.z & 0xffff0000u));
                    m6 = fmaxf(m6, __uint_as_float(v.w << 16));
                    m7 = fmaxf(m7, __uint_as_float(v.w & 0xffff0000u));
                }
            }
        } else {
            for (int k = 0; k < kk; ++k) {
                const int s = src[(size_t)row * 16 + k];
                const uint4 v = *(const uint4*)(slab + (size_t)s * 32 + c8);
                m0 = fmaxf(m0, __uint_as_float(v.x << 16));
                m1 = fmaxf(m1, __uint_as_float(v.x & 0xffff0000u));
                m2 = fmaxf(m2, __uint_as_float(v.y << 16));
                m3 = fmaxf(m3, __uint_as_float(v.y & 0xffff0000u));
                m4 = fmaxf(m4, __uint_as_float(v.z << 16));
                m5 = fmaxf(m5, __uint_as_float(v.z & 0xffff0000u));
                m6 = fmaxf(m6, __uint_as_float(v.w << 16));
                m7 = fmaxf(m7, __uint_as_float(v.w & 0xffff0000u));
            }
        }

        float* op = out + (size_t)row * 512 + slice * 32 + c8;
        const f32x4 d0 = __builtin_nontemporal_load((const f32x4*)op);
        const f32x4 d1 = __builtin_nontemporal_load((const f32x4*)op + 1);
        f32x4 o0, o1;
        o0[0] = m0 + d0[0]; o0[1] = m1 + d0[1]; o0[2] = m2 + d0[2]; o0[3] = m3 + d0[3];
        o1[0] = m4 + d1[0]; o1[1] = m5 + d1[1]; o1[2] = m6 + d1[2]; o1[3] = m7 + d1[3];
        __builtin_nontemporal_store(o0, (f32x4*)op);
        __builtin_nontemporal_store(o1, (f32x4*)op + 1);
    }
}

extern "C" void kernel_launch(void* const* d_in, const int* in_sizes, int n_in,
                              void* d_out, int out_size, void* d_ws, size_t ws_size,
                              hipStream_t stream) {
    const int*   kptr = (const int*)d_in[0];
    const int*   src  = (const int*)d_in[1];
    const float* feat = (const float*)d_in[2];
    const float* Wth  = (const float*)d_in[3];
    const float* Wph  = (const float*)d_in[4];
    float* out = (float*)d_out;

    const int N = in_sizes[2] / 512;            // 65536
    const size_t slabStride = (size_t)N * 32;   // elems per 32-col slab

    // ws layout: featb 64MB | wtc 1MB | theta slabs 64MB  (129 MB total)
    unsigned short* featb = (unsigned short*)d_ws;
    unsigned short* wtc   = (unsigned short*)((char*)d_ws + (size_t)64 * 1024 * 1024);
    unsigned short* table = (unsigned short*)((char*)d_ws + (size_t)65 * 1024 * 1024);

    const int chunksPerSlice = N / 512;

    k_convert_feat<<<(N * 512) / 1024, 256, 0, stream>>>(feat, featb);
    k_prep_w<<<512, 256, 0, stream>>>(Wth, Wph, wtc);
    k_gemm<<<(N / 128) * 8, 256, 0, stream>>>(featb, wtc, table, out, slabStride);
    k_gather<<<16 * chunksPerSlice, 256, 0, stream>>>(table, out, src, kptr,
                                                      chunksPerSlice, slabStride);
}